// Round 2
// baseline (1221.459 us; speedup 1.0000x reference)
//
#include <hip/hip_runtime.h>

typedef float f32x4 __attribute__((ext_vector_type(4)));
typedef float f32x2 __attribute__((ext_vector_type(2)));
typedef short s16x8 __attribute__((ext_vector_type(8)));
typedef __bf16 bf16x8 __attribute__((ext_vector_type(8)));

__device__ __forceinline__ unsigned short f2bf(float f) {
    unsigned int u = __builtin_bit_cast(unsigned int, f);
    u += 0x7FFFu + ((u >> 16) & 1u);
    return (unsigned short)(u >> 16);
}

__device__ __forceinline__ f32x4 MFMA(s16x8 a, s16x8 b, f32x4 c) {
    return __builtin_amdgcn_mfma_f32_16x16x32_bf16(
        __builtin_bit_cast(bf16x8, a), __builtin_bit_cast(bf16x8, b), c, 0, 0, 0);
}

__device__ __forceinline__ float sigm(float v) {
    return __builtin_amdgcn_rcpf(1.f + __builtin_amdgcn_exp2f(-1.4426950408889634f * v));
}
__device__ __forceinline__ float tanh_(float v) {
    return 2.f * __builtin_amdgcn_rcpf(1.f + __builtin_amdgcn_exp2f(-2.8853900817779268f * v)) - 1.f;
}

// ---------------- prologue kernels ----------------

// WC[j,f] = sum_e Wih1[j,e] * W_enc[e,f]; benc[j] = sum_e Wih1[j,e] * b_enc[e]
__global__ void wc_kernel(const float* __restrict__ Wih1, const float* __restrict__ W_enc,
                          const float* __restrict__ b_enc, float* __restrict__ WC,
                          float* __restrict__ benc) {
    int i = blockIdx.x * 256 + threadIdx.x;
    if (i >= 1024 * 35) return;
    int j = i / 35;
    int f = i - j * 35;
    const float* wr = Wih1 + j * 256;
    float s = 0.f;
    if (f < 34) {
        for (int e = 0; e < 256; ++e) s += wr[e] * W_enc[e * 34 + f];
        WC[j * 34 + f] = s;
    } else {
        for (int e = 0; e < 256; ++e) s += wr[e] * b_enc[e];
        benc[j] = s;
    }
}

// Pack W (row-major [srcRows, srcK]) into per-wave-sequential bf16 B-frag streams:
// linear s16x8 index ((ntb*KK + kk)*G + g)*64 + lane holds
//   W[g*gStride + ntb*16 + (lane&15)][kk*32 + (lane>>4)*8 + j]  (0 outside bounds)
__global__ void pack_kernel(const float* __restrict__ src, unsigned short* __restrict__ dst,
                            int NTB, int KK, int G, int gStride, int srcRows, int srcK) {
    int idx = blockIdx.x * 256 + threadIdx.x;
    int total = NTB * KK * G * 64;
    if (idx >= total) return;
    int lane = idx & 63, q = idx >> 6;
    int g = q % G; q /= G;
    int kk = q % KK;
    int ntb = q / KK;
    int row = g * gStride + ntb * 16 + (lane & 15);
    int kbase = kk * 32 + ((lane >> 4) & 3) * 8;
    s16x8 v;
    #pragma unroll
    for (int j = 0; j < 8; ++j) {
        int k = kbase + j;
        float fv = (row < srcRows && k < srcK) ? src[row * srcK + k] : 0.f;
        v[j] = (short)f2bf(fv);
    }
    *(s16x8*)(dst + (long)idx * 8) = v;
}

__global__ void bias_kernel(const float* bih1, const float* bhh1, const float* benc,
                            const float* bih2, const float* bhh2, const float* b_dec,
                            float* bs1a, float* bs1b, float* bs2, float* bdec) {
    int j = blockIdx.x * 256 + threadIdx.x;
    if (j < 1024) {
        float s = bih1[j] + bhh1[j];
        bs1a[j] = s + benc[j];
        bs1b[j] = s;
        bs2[j] = bih2[j] + bhh2[j];
    }
    if (j < 48) bdec[j] = (j < 34) ? b_dec[j] : 0.f;
}

// ---------------- fused LSTM kernel ----------------

// One LSTM cell for this block's 64 rows. Input path (KKIN k-tiles of 32) then hidden
// path (8 k-tiles) as one stream. B (weights, global/L2, ~200-500cy latency) uses a
// depth-4 ring: loads issued ~4 compute-groups (~310cy of MFMA) before use. A (LDS,
// ~120cy) uses a depth-2 ring. All ring indices are compile-time (rule: runtime-indexed
// register arrays go to scratch). Writes new h to Hout (the OTHER h buffer) -> only
// ONE barrier per cell_step (double-buffered h removes the read-drain barrier).
template<int KKIN>
__device__ __forceinline__ void cell_step(
    const unsigned short* Ain, int ainStride,
    const unsigned short* Ahid,
    const unsigned short* __restrict__ pWin,
    const unsigned short* __restrict__ pWhid,
    const float* __restrict__ Lbias, float (&cst)[2][4][4], unsigned short* Hout,
    int wave, int lane, int ln15, int quad) {
    constexpr int TOTAL = KKIN + 8;  // 10 or 16
    #pragma unroll
    for (int s = 0; s < 2; ++s) {
        const int ntb = wave * 2 + s;
        const s16x8* wIn  = (const s16x8*)pWin  + ntb * KKIN * 256 + lane;
        const s16x8* wHid = (const s16x8*)pWhid + ntb * 8 * 256 + lane;
        f32x4 acc[4][4];
        #pragma unroll
        for (int g = 0; g < 4; ++g)
            #pragma unroll
            for (int mt = 0; mt < 4; ++mt) acc[g][mt] = f32x4{0.f, 0.f, 0.f, 0.f};
        s16x8 B0[4], B1[4], B2[4], B3[4], A0[4], A1[4];
        auto loadB = [&](int u, s16x8 (&Bs)[4]) {
            const s16x8* p = (u < KKIN) ? (wIn + u * 256) : (wHid + (u - KKIN) * 256);
            Bs[0] = p[0]; Bs[1] = p[64]; Bs[2] = p[128]; Bs[3] = p[192];
        };
        auto loadA = [&](int u, s16x8 (&As)[4]) {
            const unsigned short* ap; int st;
            if (u < KKIN) { ap = Ain + u * 32; st = ainStride; }
            else          { ap = Ahid + (u - KKIN) * 32; st = 264; }
            #pragma unroll
            for (int mt = 0; mt < 4; ++mt)
                As[mt] = *(const s16x8*)(ap + (mt * 16 + ln15) * st + quad * 8);
        };
        auto comp = [&](s16x8 (&Bs)[4], s16x8 (&As)[4]) {
            #pragma unroll
            for (int g = 0; g < 4; ++g)
                #pragma unroll
                for (int mt = 0; mt < 4; ++mt) acc[g][mt] = MFMA(As[mt], Bs[g], acc[g][mt]);
        };
        // preamble: 4 B-tiles + 2 A-tiles in flight
        loadB(0, B0); loadB(1, B1); loadB(2, B2); loadB(3, B3);
        loadA(0, A0); loadA(1, A1);
        #pragma unroll 1
        for (int t = 0; t < (TOTAL & ~3); t += 4) {
            comp(B0, A0);
            if (t + 4 < TOTAL) loadB(t + 4, B0);
            loadA(t + 2, A0);
            comp(B1, A1);
            if (t + 5 < TOTAL) loadB(t + 5, B1);
            loadA(t + 3, A1);
            comp(B2, A0);
            if (t + 6 < TOTAL) loadB(t + 6, B2);
            if (t + 4 < TOTAL) loadA(t + 4, A0);
            comp(B3, A1);
            if (t + 7 < TOTAL) loadB(t + 7, B3);
            if (t + 5 < TOTAL) loadA(t + 5, A1);
        }
        if constexpr ((TOTAL & 3) != 0) {  // TOTAL=10: tail tiles 8,9 sit in B0/B1, A0/A1
            comp(B0, A0);
            comp(B1, A1);
        }
        const int colB = ntb * 16 + ln15;
        const float bi = Lbias[colB], bff = Lbias[256 + colB];
        const float bg = Lbias[512 + colB], bo = Lbias[768 + colB];
        #pragma unroll
        for (int mt = 0; mt < 4; ++mt) {
            #pragma unroll
            for (int r = 0; r < 4; ++r) {
                float iv = acc[0][mt][r] + bi;
                float fv = acc[1][mt][r] + bff;
                float gv = acc[2][mt][r] + bg;
                float ov = acc[3][mt][r] + bo;
                float cn = sigm(fv) * cst[s][mt][r] + sigm(iv) * tanh_(gv);
                cst[s][mt][r] = cn;
                float hv = sigm(ov) * tanh_(cn);
                Hout[(mt * 16 + quad * 4 + r) * 264 + colB] = f2bf(hv);
            }
        }
    }
    __syncthreads();  // new h visible (double-buffered: no pre-write drain barrier needed)
}

// LDS: h1[2] + h2[2] double-buffered (4 x 33792) + scratch 12288 + Lbd 256 = 147712 B.
// Still 1 block/CU (grid == 256 == CU count), which LDS already forced anyway.
__global__ __launch_bounds__(512, 1) void lstm_fused(
    const float* __restrict__ x,
    const unsigned short* __restrict__ pWC,
    const unsigned short* __restrict__ pWih1,
    const unsigned short* __restrict__ pWhh1,
    const unsigned short* __restrict__ pWih2,
    const unsigned short* __restrict__ pWhh2,
    const unsigned short* __restrict__ pWdec,
    const float* __restrict__ gb1a, const float* __restrict__ gb1b,
    const float* __restrict__ gb2, const float* __restrict__ gbd,
    float* __restrict__ out) {
    extern __shared__ unsigned char smem[];
    unsigned short* h1lo = (unsigned short*)smem;      // parity 0
    unsigned short* h1hi = h1lo + 64 * 264;            // parity 1
    unsigned short* h2lo = h1hi + 64 * 264;
    unsigned short* h2hi = h2lo + 64 * 264;
    unsigned char* scratch = (unsigned char*)(h2hi + 64 * 264);  // 12288 B union:
    unsigned short* xbuf = (unsigned short*)scratch;   //   obs: 64 x 72 bf16 (zero-padded)
    float* dOut = (float*)scratch;                     //   dec: 64 x 48 f32 (cumsum state lives here)
    float* Lbd = (float*)(scratch + 12288);            // 48 used

    const int tid = threadIdx.x;
    const int wave = tid >> 6;
    const int lane = tid & 63;
    const int ln15 = lane & 15;
    const int quad = lane >> 4;
    const int m0 = blockIdx.x * 64;

    for (int i = tid; i < 4 * 64 * 264 / 2; i += 512) ((int*)h1lo)[i] = 0;  // all 4 h buffers
    for (int i = tid; i < 3072; i += 512) ((int*)scratch)[i] = 0;
    if (tid < 48) Lbd[tid] = gbd[tid];

    float c1[2][4][4], c2[2][4][4];
    #pragma unroll
    for (int s = 0; s < 2; ++s)
        #pragma unroll
        for (int mt = 0; mt < 4; ++mt)
            #pragma unroll
            for (int r = 0; r < 4; ++r) { c1[s][mt][r] = 0.f; c2[s][mt][r] = 0.f; }

    __syncthreads();

    #pragma unroll 1
    for (int t = 0; t < 19; ++t) {
        const int cur = t & 1;
        unsigned short* h1w = cur ? h1hi : h1lo;
        const unsigned short* h1r = cur ? h1lo : h1hi;
        unsigned short* h2w = cur ? h2hi : h2lo;
        const unsigned short* h2r = cur ? h2lo : h2hi;

        if (t < 10) {
            // stage x_t -> xbuf (bf16; cols 34..63 stay zero). Non-temporal: keep L2 for weights.
            for (int i = tid; i < 1088; i += 512) {
                int r = i / 17, p = i - r * 17;
                f32x2 v = __builtin_nontemporal_load((const f32x2*)(x + (m0 + r) * 340 + t * 34) + p);
                xbuf[r * 72 + p * 2]     = f2bf(v.x);
                xbuf[r * 72 + p * 2 + 1] = f2bf(v.y);
            }
            __syncthreads();
            cell_step<2>(xbuf, 72, h1r, pWC, pWhh1, gb1a, c1, h1w, wave, lane, ln15, quad);
        } else {
            cell_step<8>(h2r, 264, h1r, pWih1, pWhh1, gb1b, c1, h1w, wave, lane, ln15, quad);
        }
        cell_step<8>(h1w, 264, h2r, pWih2, pWhh2, gb2, c2, h2w, wave, lane, ln15, quad);

        if (t >= 9) {
            const int tout = t - 9;
            if (wave < 3) {  // decoder: dec = h2 @ W_dec^T + b_dec ; cumsum in dOut (LDS)
                f32x4 d[4];
                #pragma unroll
                for (int mt = 0; mt < 4; ++mt) d[mt] = f32x4{0.f, 0.f, 0.f, 0.f};
                #pragma unroll
                for (int kk = 0; kk < 8; ++kk) {
                    s16x8 b = *((const s16x8*)pWdec + (wave * 8 + kk) * 64 + lane);
                    #pragma unroll
                    for (int mt = 0; mt < 4; ++mt) {
                        s16x8 a = *(const s16x8*)(h2w + (mt * 16 + ln15) * 264 + kk * 32 + quad * 8);
                        d[mt] = MFMA(a, b, d[mt]);
                    }
                }
                const int col = wave * 16 + ln15;
                const bool valid = (col < 34);
                const float bd = Lbd[col];
                #pragma unroll
                for (int mt = 0; mt < 4; ++mt) {
                    #pragma unroll
                    for (int r = 0; r < 4; ++r) {
                        const int rloc = mt * 16 + quad * 4 + r;
                        float v = d[mt][r] + bd;
                        if (tout == 0) {
                            float xr = valid ? __builtin_nontemporal_load(x + (m0 + rloc) * 340 + 306 + col) : 0.f;
                            dOut[rloc * 48 + col] = v + xr;
                        } else {
                            dOut[rloc * 48 + col] += v;  // cumsum state in LDS (frees 16 VGPRs)
                        }
                    }
                }
            }
            __syncthreads();
            // contiguous per-row non-temporal stores (write-combine friendly)
            for (int i = tid; i < 1088; i += 512) {
                int r = i / 17, p = i - r * 17;
                f32x2 v = *(const f32x2*)(dOut + r * 48 + p * 2);
                __builtin_nontemporal_store(v, (f32x2*)(out + (m0 + r) * 340 + tout * 34) + p);
            }
            // no barrier needed: dOut is rewritten only after cell barriers of step t+1
        }
    }
}

// ---------------- launch ----------------

extern "C" void kernel_launch(void* const* d_in, const int* in_sizes, int n_in,
                              void* d_out, int out_size, void* d_ws, size_t ws_size,
                              hipStream_t stream) {
    const float* x     = (const float*)d_in[0];
    const float* W_enc = (const float*)d_in[1];
    const float* b_enc = (const float*)d_in[2];
    const float* Wih1  = (const float*)d_in[3];
    const float* Whh1  = (const float*)d_in[4];
    const float* bih1  = (const float*)d_in[5];
    const float* bhh1  = (const float*)d_in[6];
    const float* Wih2  = (const float*)d_in[7];
    const float* Whh2  = (const float*)d_in[8];
    const float* bih2  = (const float*)d_in[9];
    const float* bhh2  = (const float*)d_in[10];
    const float* W_dec = (const float*)d_in[11];
    const float* b_dec = (const float*)d_in[12];
    float* out = (float*)d_out;

    unsigned char* w = (unsigned char*)d_ws;
    float* WC   = (float*)(w + 0);         // 139264
    float* benc = (float*)(w + 139264);    // 4096
    float* bs1a = (float*)(w + 143360);
    float* bs1b = (float*)(w + 147456);
    float* bs2  = (float*)(w + 151552);
    float* bdec = (float*)(w + 155648);    // 256
    unsigned short* pWC   = (unsigned short*)(w + 155904);   // 16*2*4*64*16 = 131072
    unsigned short* pWih1 = (unsigned short*)(w + 286976);   // 524288 each
    unsigned short* pWhh1 = (unsigned short*)(w + 811264);
    unsigned short* pWih2 = (unsigned short*)(w + 1335552);
    unsigned short* pWhh2 = (unsigned short*)(w + 1859840);
    unsigned short* pWdec = (unsigned short*)(w + 2384128);  // 24576

    wc_kernel<<<140, 256, 0, stream>>>(Wih1, W_enc, b_enc, WC, benc);
    pack_kernel<<<32, 256, 0, stream>>>(WC, pWC, 16, 2, 4, 256, 1024, 34);
    pack_kernel<<<128, 256, 0, stream>>>(Wih1, pWih1, 16, 8, 4, 256, 1024, 256);
    pack_kernel<<<128, 256, 0, stream>>>(Whh1, pWhh1, 16, 8, 4, 256, 1024, 256);
    pack_kernel<<<128, 256, 0, stream>>>(Wih2, pWih2, 16, 8, 4, 256, 1024, 256);
    pack_kernel<<<128, 256, 0, stream>>>(Whh2, pWhh2, 16, 8, 4, 256, 1024, 256);
    pack_kernel<<<6, 256, 0, stream>>>(W_dec, pWdec, 3, 8, 1, 0, 34, 256);
    bias_kernel<<<4, 256, 0, stream>>>(bih1, bhh1, benc, bih2, bhh2, b_dec, bs1a, bs1b, bs2, bdec);

    hipFuncSetAttribute((const void*)lstm_fused, hipFuncAttributeMaxDynamicSharedMemorySize, 147712);
    lstm_fused<<<256, 512, 147712, stream>>>(x, pWC, pWih1, pWhh1, pWih2, pWhh2, pWdec,
                                             bs1a, bs1b, bs2, bdec, out);
}

// Round 3
// 911.112 us; speedup vs baseline: 1.3406x; 1.3406x over previous
//
#include <hip/hip_runtime.h>

typedef float f32x4 __attribute__((ext_vector_type(4)));
typedef float f32x2 __attribute__((ext_vector_type(2)));
typedef short s16x8 __attribute__((ext_vector_type(8)));
typedef __bf16 bf16x8 __attribute__((ext_vector_type(8)));

__device__ __forceinline__ unsigned short f2bf(float f) {
    unsigned int u = __builtin_bit_cast(unsigned int, f);
    u += 0x7FFFu + ((u >> 16) & 1u);
    return (unsigned short)(u >> 16);
}

__device__ __forceinline__ f32x4 MFMA(s16x8 a, s16x8 b, f32x4 c) {
    return __builtin_amdgcn_mfma_f32_16x16x32_bf16(
        __builtin_bit_cast(bf16x8, a), __builtin_bit_cast(bf16x8, b), c, 0, 0, 0);
}

__device__ __forceinline__ float sigm(float v) {
    return __builtin_amdgcn_rcpf(1.f + __builtin_amdgcn_exp2f(-1.4426950408889634f * v));
}
__device__ __forceinline__ float tanh_(float v) {
    return 2.f * __builtin_amdgcn_rcpf(1.f + __builtin_amdgcn_exp2f(-2.8853900817779268f * v)) - 1.f;
}

// async global->LDS: per-lane global src (base + lane*16B), wave-uniform LDS base,
// HW writes lds_base + lane*16. Zero VGPRs held for in-flight data.
__device__ __forceinline__ void async_issue(const unsigned short* src, unsigned short* ldsDst,
                                            int lane) {
    __builtin_amdgcn_global_load_lds(
        (const __attribute__((address_space(1))) void*)(src + lane * 8),
        (__attribute__((address_space(3))) void*)ldsDst, 16, 0, 0);
}

// ---------------- prologue kernels ----------------

__global__ void wc_kernel(const float* __restrict__ Wih1, const float* __restrict__ W_enc,
                          const float* __restrict__ b_enc, float* __restrict__ WC,
                          float* __restrict__ benc) {
    int i = blockIdx.x * 256 + threadIdx.x;
    if (i >= 1024 * 35) return;
    int j = i / 35;
    int f = i - j * 35;
    const float* wr = Wih1 + j * 256;
    float s = 0.f;
    if (f < 34) {
        for (int e = 0; e < 256; ++e) s += wr[e] * W_enc[e * 34 + f];
        WC[j * 34 + f] = s;
    } else {
        for (int e = 0; e < 256; ++e) s += wr[e] * b_enc[e];
        benc[j] = s;
    }
}

// Pack W (row-major [srcRows, srcK]) into per-wave-sequential bf16 B-frag streams:
// linear s16x8 index ((ntb*KK + kk)*G + g)*64 + lane holds
//   W[g*gStride + ntb*16 + (lane&15)][kk*32 + (lane>>4)*8 + j]  (0 outside bounds)
__global__ void pack_kernel(const float* __restrict__ src, unsigned short* __restrict__ dst,
                            int NTB, int KK, int G, int gStride, int srcRows, int srcK) {
    int idx = blockIdx.x * 256 + threadIdx.x;
    int total = NTB * KK * G * 64;
    if (idx >= total) return;
    int lane = idx & 63, q = idx >> 6;
    int g = q % G; q /= G;
    int kk = q % KK;
    int ntb = q / KK;
    int row = g * gStride + ntb * 16 + (lane & 15);
    int kbase = kk * 32 + ((lane >> 4) & 3) * 8;
    s16x8 v;
    #pragma unroll
    for (int j = 0; j < 8; ++j) {
        int k = kbase + j;
        float fv = (row < srcRows && k < srcK) ? src[row * srcK + k] : 0.f;
        v[j] = (short)f2bf(fv);
    }
    *(s16x8*)(dst + (long)idx * 8) = v;
}

__global__ void bias_kernel(const float* bih1, const float* bhh1, const float* benc,
                            const float* bih2, const float* bhh2, const float* b_dec,
                            float* bs1a, float* bs1b, float* bs2, float* bdec) {
    int j = blockIdx.x * 256 + threadIdx.x;
    if (j < 1024) {
        float s = bih1[j] + bhh1[j];
        bs1a[j] = s + benc[j];
        bs1b[j] = s;
        bs2[j] = bih2[j] + bhh2[j];
    }
    if (j < 48) bdec[j] = (j < 34) ? b_dec[j] : 0.f;
}

// ---------------- fused LSTM kernel ----------------

// One g-unit: issue one async B sub-stage (distance 6 ahead), counted-vmcnt wait,
// ds_read the landed B fragment, 4 MFMAs. vmcnt(6): the read slot's load is the
// 7th-newest VMEM op (6 newer sub-stage loads outstanding) -> wait guarantees it
// landed. FIFO vmcnt retirement makes the count exact; older VMEM (stores, x loads)
// retires first and cannot break the guarantee.
#define GUNIT_ISSUE(g, srcp, islot, rslot, Areg)                               \
    {                                                                          \
        async_issue((srcp), Bst + (islot) * 512, lane);                        \
        asm volatile("s_waitcnt vmcnt(6)" ::: "memory");                       \
        s16x8 b = *(const s16x8*)(Bst + (rslot) * 512 + lane * 8);             \
        acc[g][0] = MFMA(Areg[0], b, acc[g][0]);                               \
        acc[g][1] = MFMA(Areg[1], b, acc[g][1]);                               \
        acc[g][2] = MFMA(Areg[2], b, acc[g][2]);                               \
        acc[g][3] = MFMA(Areg[3], b, acc[g][3]);                               \
    }

#define GUNIT_WAIT(g, N, rslot, Areg)                                         \
    {                                                                          \
        asm volatile("s_waitcnt vmcnt(" #N ")" ::: "memory");                  \
        s16x8 b = *(const s16x8*)(Bst + (rslot) * 512 + lane * 8);             \
        acc[g][0] = MFMA(Areg[0], b, acc[g][0]);                               \
        acc[g][1] = MFMA(Areg[1], b, acc[g][1]);                               \
        acc[g][2] = MFMA(Areg[2], b, acc[g][2]);                               \
        acc[g][3] = MFMA(Areg[3], b, acc[g][3]);                               \
    }

// One LSTM cell for this block's 64 rows. B (weights) streams through a per-wave
// 8-slot x 1KB LDS ring via async global_load_lds (no B registers in flight);
// A (activations) via depth-2 register ring from LDS. Flattened sub-stage index
// w = (s*T + u)*4 + g; issue distance 6; slots = w & 7 (compile-time literals
// since units advance 4 per u). Stages for s=1 are issued during s=0's tail and
// keep landing through the s=0 epilogue.
template<int KKIN>
__device__ __forceinline__ void cell_step(
    const unsigned short* Ain, int ainStride,
    const unsigned short* Ahid,
    const unsigned short* __restrict__ pWin,
    const unsigned short* __restrict__ pWhid,
    const float* Lbias, float (&cst)[2][4][4], unsigned short* Hout,
    unsigned short* Bst, int wave, int lane, int ln15, int quad) {
    constexpr int T = KKIN + 8;  // 10 or 16 (even)
    unsigned int hp[2][8];
    const int wv2 = wave * 2;

    auto baseFor = [&](int v) -> const unsigned short* {  // v in [0, 2T)
        int ss = (v >= T) ? 1 : 0;
        int uu = v - ss * T;
        int ntb = wv2 + ss;
        return (uu < KKIN) ? pWin + (ntb * KKIN + uu) * 2048
                           : pWhid + (ntb * 8 + uu - KKIN) * 2048;
    };
    auto loadA = [&](int u, s16x8 (&As)[4]) {
        const unsigned short* ap; int st;
        if (u < KKIN) { ap = Ain + u * 32; st = ainStride; }
        else          { ap = Ahid + (u - KKIN) * 32; st = 264; }
        #pragma unroll
        for (int mt = 0; mt < 4; ++mt)
            As[mt] = *(const s16x8*)(ap + (mt * 16 + ln15) * st + quad * 8);
    };

    // prologue: stage sub-units 0..5 (v=0 g0..3, v=1 g0,g1) into slots 0..5.
    // Empty asm fences pin issue order (vmcnt counting relies on program order).
    {
        const unsigned short* b0 = baseFor(0);
        const unsigned short* b1 = baseFor(1);
        async_issue(b0,        Bst + 0 * 512, lane); asm volatile("" ::: "memory");
        async_issue(b0 + 512,  Bst + 1 * 512, lane); asm volatile("" ::: "memory");
        async_issue(b0 + 1024, Bst + 2 * 512, lane); asm volatile("" ::: "memory");
        async_issue(b0 + 1536, Bst + 3 * 512, lane); asm volatile("" ::: "memory");
        async_issue(b1,        Bst + 4 * 512, lane); asm volatile("" ::: "memory");
        async_issue(b1 + 512,  Bst + 5 * 512, lane); asm volatile("" ::: "memory");
    }

    #pragma unroll
    for (int s = 0; s < 2; ++s) {
        f32x4 acc[4][4];
        #pragma unroll
        for (int g = 0; g < 4; ++g)
            #pragma unroll
            for (int mt = 0; mt < 4; ++mt) acc[g][mt] = f32x4{0.f, 0.f, 0.f, 0.f};
        s16x8 A0[4], A1[4];
        loadA(0, A0); loadA(1, A1);

        const int ulim = (s == 0) ? T : T - 2;  // s=1: last pair peeled (drain)
        #pragma unroll 1
        for (int u = 0; u < ulim; u += 2) {
            const int v = s * T + u;
            const unsigned short* bn1 = baseFor(v + 1);
            const unsigned short* bn2 = baseFor(v + 2);
            // even u: read slots 0..3, issue units w+6 -> slots 6,7,0,1
            GUNIT_ISSUE(0, bn1 + 1024, 6, 0, A0)
            GUNIT_ISSUE(1, bn1 + 1536, 7, 1, A0)
            GUNIT_ISSUE(2, bn2,        0, 2, A0)
            GUNIT_ISSUE(3, bn2 + 512,  1, 3, A0)
            if (u + 2 < T) loadA(u + 2, A0);
            const unsigned short* bn3 = baseFor(v + 3);
            // odd u+1: read slots 4..7, issue -> slots 2,3,4,5
            GUNIT_ISSUE(0, bn2 + 1024, 2, 4, A1)
            GUNIT_ISSUE(1, bn2 + 1536, 3, 5, A1)
            GUNIT_ISSUE(2, bn3,        4, 6, A1)
            GUNIT_ISSUE(3, bn3 + 512,  5, 7, A1)
            if (u + 3 < T) loadA(u + 3, A1);
        }
        if (s == 1) {
            // peel u=T-2: issues for the last two units (W-2,W-1), then drain counts
            const unsigned short* bl = baseFor(2 * T - 1);
            GUNIT_ISSUE(0, bl + 1024, 6, 0, A0)
            GUNIT_ISSUE(1, bl + 1536, 7, 1, A0)
            GUNIT_WAIT(2, 5, 2, A0)
            GUNIT_WAIT(3, 4, 3, A0)
            // peel u=T-1: pure drain
            GUNIT_WAIT(0, 3, 4, A1)
            GUNIT_WAIT(1, 2, 5, A1)
            GUNIT_WAIT(2, 1, 6, A1)
            GUNIT_WAIT(3, 0, 7, A1)
        }

        const int colB = (wv2 + s) * 16 + ln15;
        const float bi = Lbias[colB], bff = Lbias[256 + colB];
        const float bg = Lbias[512 + colB], bo = Lbias[768 + colB];
        #pragma unroll
        for (int mt = 0; mt < 4; ++mt) {
            #pragma unroll
            for (int r = 0; r < 4; ++r) {
                float iv = acc[0][mt][r] + bi;
                float fv = acc[1][mt][r] + bff;
                float gv = acc[2][mt][r] + bg;
                float ov = acc[3][mt][r] + bo;
                float cn = sigm(fv) * cst[s][mt][r] + sigm(iv) * tanh_(gv);
                cst[s][mt][r] = cn;
                float hv = sigm(ov) * tanh_(cn);
                unsigned int hb = (unsigned int)f2bf(hv);
                if ((r & 1) == 0) hp[s][mt * 2 + (r >> 1)] = hb;
                else              hp[s][mt * 2 + (r >> 1)] |= (hb << 16);
            }
        }
    }
    __syncthreads();  // all waves done reading h-buffers
    #pragma unroll
    for (int s = 0; s < 2; ++s)
        #pragma unroll
        for (int mt = 0; mt < 4; ++mt)
            #pragma unroll
            for (int r = 0; r < 4; ++r)
                Hout[(mt * 16 + quad * 4 + r) * 264 + (wv2 + s) * 16 + ln15] =
                    (unsigned short)(hp[s][mt * 2 + (r >> 1)] >> ((r & 1) * 16));
    __syncthreads();  // new h visible
}

// LDS: h1 33792 + h2 33792 + scratch 12288 + Lb 12288 + Lbd 256 + Bring 65536 = 157952 B.
__global__ __launch_bounds__(512, 1) void lstm_fused(
    const float* __restrict__ x,
    const unsigned short* __restrict__ pWC,
    const unsigned short* __restrict__ pWih1,
    const unsigned short* __restrict__ pWhh1,
    const unsigned short* __restrict__ pWih2,
    const unsigned short* __restrict__ pWhh2,
    const unsigned short* __restrict__ pWdec,
    const float* __restrict__ gb1a, const float* __restrict__ gb1b,
    const float* __restrict__ gb2, const float* __restrict__ gbd,
    float* __restrict__ out) {
    extern __shared__ unsigned char smem[];
    unsigned short* h1buf = (unsigned short*)smem;                // 33792 B
    unsigned short* h2buf = h1buf + 64 * 264;                     // 33792 B
    unsigned char* scratch = (unsigned char*)(h2buf + 64 * 264);  // 12288 B union:
    unsigned short* xbuf = (unsigned short*)scratch;              //   obs: 64 x 72 bf16
    float* dOut = (float*)scratch;                                //   dec: 64 x 48 f32
    float* Lb1a = (float*)(scratch + 12288);
    float* Lb1b = Lb1a + 1024;
    float* Lb2  = Lb1b + 1024;
    float* Lbd  = Lb2 + 1024;                                     // 48 used (256 B)
    unsigned short* Bring = (unsigned short*)(scratch + 12288 + 12288 + 256);  // 65536 B

    const int tid = threadIdx.x;
    const int wave = tid >> 6;
    const int lane = tid & 63;
    const int ln15 = lane & 15;
    const int quad = lane >> 4;
    const int m0 = blockIdx.x * 64;
    unsigned short* Bst = Bring + wave * 4096;  // this wave's 8KB (8 slots x 1KB)

    for (int i = tid; i < 64 * 264; i += 512) { h1buf[i] = 0; h2buf[i] = 0; }
    for (int i = tid; i < 3072; i += 512) ((int*)scratch)[i] = 0;
    for (int i = tid; i < 1024; i += 512) { Lb1a[i] = gb1a[i]; Lb1b[i] = gb1b[i]; Lb2[i] = gb2[i]; }
    if (tid < 48) Lbd[tid] = gbd[tid];

    float c1[2][4][4], c2[2][4][4];
    #pragma unroll
    for (int s = 0; s < 2; ++s)
        #pragma unroll
        for (int mt = 0; mt < 4; ++mt)
            #pragma unroll
            for (int r = 0; r < 4; ++r) { c1[s][mt][r] = 0.f; c2[s][mt][r] = 0.f; }

    __syncthreads();

    #pragma unroll 1
    for (int t = 0; t < 19; ++t) {
        if (t < 10) {
            // stage x_t -> xbuf (bf16; cols 34..63 stay zero)
            for (int i = tid; i < 1088; i += 512) {
                int r = i / 17, p = i - r * 17;
                f32x2 v = __builtin_nontemporal_load((const f32x2*)(x + (m0 + r) * 340 + t * 34) + p);
                xbuf[r * 72 + p * 2]     = f2bf(v.x);
                xbuf[r * 72 + p * 2 + 1] = f2bf(v.y);
            }
            __syncthreads();
            cell_step<2>(xbuf, 72, h1buf, pWC, pWhh1, Lb1a, c1, h1buf, Bst, wave, lane, ln15, quad);
        } else {
            cell_step<8>(h2buf, 264, h1buf, pWih1, pWhh1, Lb1b, c1, h1buf, Bst, wave, lane, ln15, quad);
        }
        cell_step<8>(h1buf, 264, h2buf, pWih2, pWhh2, Lb2, c2, h2buf, Bst, wave, lane, ln15, quad);

        if (t >= 9) {
            const int tout = t - 9;
            if (wave < 3) {  // decoder: dec = h2 @ W_dec^T + b_dec ; cumsum in dOut (LDS)
                f32x4 d[4];
                #pragma unroll
                for (int mt = 0; mt < 4; ++mt) d[mt] = f32x4{0.f, 0.f, 0.f, 0.f};
                #pragma unroll
                for (int kk = 0; kk < 8; ++kk) {
                    s16x8 b = *((const s16x8*)pWdec + (wave * 8 + kk) * 64 + lane);
                    #pragma unroll
                    for (int mt = 0; mt < 4; ++mt) {
                        s16x8 a = *(const s16x8*)(h2buf + (mt * 16 + ln15) * 264 + kk * 32 + quad * 8);
                        d[mt] = MFMA(a, b, d[mt]);
                    }
                }
                const int col = wave * 16 + ln15;
                const bool valid = (col < 34);
                const float bd = Lbd[col];
                #pragma unroll
                for (int mt = 0; mt < 4; ++mt) {
                    #pragma unroll
                    for (int r = 0; r < 4; ++r) {
                        const int rloc = mt * 16 + quad * 4 + r;
                        float v = d[mt][r] + bd;
                        if (tout == 0) {
                            float xr = valid ? __builtin_nontemporal_load(x + (m0 + rloc) * 340 + 306 + col) : 0.f;
                            dOut[rloc * 48 + col] = v + xr;
                        } else {
                            dOut[rloc * 48 + col] += v;
                        }
                    }
                }
            }
            __syncthreads();
            // contiguous per-row non-temporal stores
            for (int i = tid; i < 1088; i += 512) {
                int r = i / 17, p = i - r * 17;
                f32x2 v = *(const f32x2*)(dOut + r * 48 + p * 2);
                __builtin_nontemporal_store(v, (f32x2*)(out + (m0 + r) * 340 + tout * 34) + p);
            }
            // no barrier needed: dOut is rewritten only after cell barriers of step t+1
        }
    }
}

#undef GUNIT_ISSUE
#undef GUNIT_WAIT

// ---------------- launch ----------------

extern "C" void kernel_launch(void* const* d_in, const int* in_sizes, int n_in,
                              void* d_out, int out_size, void* d_ws, size_t ws_size,
                              hipStream_t stream) {
    const float* x     = (const float*)d_in[0];
    const float* W_enc = (const float*)d_in[1];
    const float* b_enc = (const float*)d_in[2];
    const float* Wih1  = (const float*)d_in[3];
    const float* Whh1  = (const float*)d_in[4];
    const float* bih1  = (const float*)d_in[5];
    const float* bhh1  = (const float*)d_in[6];
    const float* Wih2  = (const float*)d_in[7];
    const float* Whh2  = (const float*)d_in[8];
    const float* bih2  = (const float*)d_in[9];
    const float* bhh2  = (const float*)d_in[10];
    const float* W_dec = (const float*)d_in[11];
    const float* b_dec = (const float*)d_in[12];
    float* out = (float*)d_out;

    unsigned char* w = (unsigned char*)d_ws;
    float* WC   = (float*)(w + 0);         // 139264
    float* benc = (float*)(w + 139264);    // 4096
    float* bs1a = (float*)(w + 143360);
    float* bs1b = (float*)(w + 147456);
    float* bs2  = (float*)(w + 151552);
    float* bdec = (float*)(w + 155648);    // 256
    unsigned short* pWC   = (unsigned short*)(w + 155904);   // 131072
    unsigned short* pWih1 = (unsigned short*)(w + 286976);   // 524288 each
    unsigned short* pWhh1 = (unsigned short*)(w + 811264);
    unsigned short* pWih2 = (unsigned short*)(w + 1335552);
    unsigned short* pWhh2 = (unsigned short*)(w + 1859840);
    unsigned short* pWdec = (unsigned short*)(w + 2384128);  // 24576

    wc_kernel<<<140, 256, 0, stream>>>(Wih1, W_enc, b_enc, WC, benc);
    pack_kernel<<<32, 256, 0, stream>>>(WC, pWC, 16, 2, 4, 256, 1024, 34);
    pack_kernel<<<128, 256, 0, stream>>>(Wih1, pWih1, 16, 8, 4, 256, 1024, 256);
    pack_kernel<<<128, 256, 0, stream>>>(Whh1, pWhh1, 16, 8, 4, 256, 1024, 256);
    pack_kernel<<<128, 256, 0, stream>>>(Wih2, pWih2, 16, 8, 4, 256, 1024, 256);
    pack_kernel<<<128, 256, 0, stream>>>(Whh2, pWhh2, 16, 8, 4, 256, 1024, 256);
    pack_kernel<<<6, 256, 0, stream>>>(W_dec, pWdec, 3, 8, 1, 0, 34, 256);
    bias_kernel<<<4, 256, 0, stream>>>(bih1, bhh1, benc, bih2, bhh2, b_dec, bs1a, bs1b, bs2, bdec);

    hipFuncSetAttribute((const void*)lstm_fused, hipFuncAttributeMaxDynamicSharedMemorySize, 157952);
    lstm_fused<<<256, 512, 157952, stream>>>(x, pWC, pWih1, pWhh1, pWih2, pWhh2, pWdec,
                                             bs1a, bs1b, bs2, bdec, out);
}